// Round 23
// baseline (308.871 us; speedup 1.0000x reference)
//
#include <hip/hip_runtime.h>
#include <hip/hip_bf16.h>
#include <math.h>

#define NFM 512   // NFMODES
#define NE  256
#define NUN 32    // NUNPAIRED
#define NM  480   // NMODES
#define NB  32    // BATCH
#define NF  288   // NE + NUN  (Ffull dim)
#define WP  16    // panel width
#define PAIRS 8   // WP/2
#define PP  18    // panel LDS pitch (even -> float2-aligned)
#define THETA 0.03125f

typedef unsigned long long ull;

// ---------------- Ja = (J - J^T)/2 ----------------
__global__ __launch_bounds__(256)
void build_ja_k(const float* __restrict__ J, float* __restrict__ Ja) {
  int t = blockIdx.x * blockDim.x + threadIdx.x;
  int stride = gridDim.x * blockDim.x;
  for (int e = t; e < NM * NM; e += stride) {
    int i = e / NM, j = e - i * NM;
    Ja[e] = 0.5f * (J[i * NM + j] - J[j * NM + i]);
  }
}

// ---------------- W (512x480) = U[:, NUN:] @ Ja  (once, batch-independent) --
__global__ __launch_bounds__(256)
void gemm_w_k(const float* __restrict__ U, const float* __restrict__ Ja,
              float* __restrict__ W) {
  const int m0 = blockIdx.y << 6;
  const int n0 = blockIdx.x << 6;
  const int tid = threadIdx.x;
  __shared__ float As[16][64];
  __shared__ float Bs[16][64];
  const int ar = tid >> 2, ac = (tid & 3) << 2;
  const int br = tid >> 4, bc = (tid & 15) << 2;
  const int tx = tid & 15, ty = tid >> 4;
  const float* Arow = U + (size_t)(m0 + ar) * NFM + NUN;
  float acc[4][4] = {};
  for (int l0 = 0; l0 < NM; l0 += 16) {
    float4 av = *(const float4*)(Arow + l0 + ac);
    As[ac + 0][ar] = av.x; As[ac + 1][ar] = av.y;
    As[ac + 2][ar] = av.z; As[ac + 3][ar] = av.w;
    float4 bv = make_float4(0.f, 0.f, 0.f, 0.f);
    if (n0 + bc < NM) bv = *(const float4*)(Ja + (size_t)(l0 + br) * NM + n0 + bc);
    *(float4*)(&Bs[br][bc]) = bv;
    __syncthreads();
#pragma unroll
    for (int kk = 0; kk < 16; ++kk) {
      float4 a4 = *(const float4*)(&As[kk][ty << 2]);
      float4 b4 = *(const float4*)(&Bs[kk][tx << 2]);
      float a[4] = {a4.x, a4.y, a4.z, a4.w};
      float bb[4] = {b4.x, b4.y, b4.z, b4.w};
#pragma unroll
      for (int q = 0; q < 4; ++q)
#pragma unroll
        for (int p = 0; p < 4; ++p) acc[q][p] = fmaf(a[q], bb[p], acc[q][p]);
    }
    __syncthreads();
  }
#pragma unroll
  for (int q = 0; q < 4; ++q) {
    int r = m0 + (ty << 2) + q;
#pragma unroll
    for (int p = 0; p < 4; ++p) {
      int m = n0 + (tx << 2) + p;
      if (m < NM) W[(size_t)r * NM + m] = acc[q][p];
    }
  }
}

// ---------------- F[b] = W[idx[b]] @ Up_b^T  -> Ffull[0:256][0:256] ---------
// Antisymmetric: only blocks by>=bx computed; off-diagonal mirror-written.
__global__ __launch_bounds__(256)
void gemm2_k(const float* __restrict__ U, const int* __restrict__ idx,
             const float* __restrict__ W, float* __restrict__ Ff) {
  const int b  = blockIdx.z;
  const int by = blockIdx.y, bx = blockIdx.x;
  if (by < bx) return;
  const int m0 = by << 6;
  const int n0 = bx << 6;
  const int tid = threadIdx.x;
  __shared__ float As[16][64];
  __shared__ float Bs[16][64];
  const int ar = tid >> 2, ac = (tid & 3) << 2;
  const int jr = tid >> 2, kc = (tid & 3) << 2;
  const int tx = tid & 15, ty = tid >> 4;
  const float* Arow = W + (size_t)idx[b * NE + m0 + ar] * NM;
  const float* Brow = U + (size_t)idx[b * NE + n0 + jr] * NFM + NUN;
  float acc[4][4] = {};
  for (int l0 = 0; l0 < NM; l0 += 16) {
    float4 av = *(const float4*)(Arow + l0 + ac);
    As[ac + 0][ar] = av.x; As[ac + 1][ar] = av.y;
    As[ac + 2][ar] = av.z; As[ac + 3][ar] = av.w;
    float4 bv = *(const float4*)(Brow + l0 + kc);
    Bs[kc + 0][jr] = bv.x; Bs[kc + 1][jr] = bv.y;
    Bs[kc + 2][jr] = bv.z; Bs[kc + 3][jr] = bv.w;
    __syncthreads();
#pragma unroll
    for (int kk = 0; kk < 16; ++kk) {
      float4 a4 = *(const float4*)(&As[kk][ty << 2]);
      float4 b4 = *(const float4*)(&Bs[kk][tx << 2]);
      float a[4] = {a4.x, a4.y, a4.z, a4.w};
      float bb[4] = {b4.x, b4.y, b4.z, b4.w};
#pragma unroll
      for (int q = 0; q < 4; ++q)
#pragma unroll
        for (int p = 0; p < 4; ++p) acc[q][p] = fmaf(a[q], bb[p], acc[q][p]);
    }
    __syncthreads();
  }
  float* Fb = Ff + (size_t)b * NF * NF;
  const bool mirror = (by > bx);
#pragma unroll
  for (int q = 0; q < 4; ++q) {
    int i = m0 + (ty << 2) + q;
#pragma unroll
    for (int p = 0; p < 4; ++p) {
      int j = n0 + (tx << 2) + p;
      Fb[(size_t)i * NF + j] = acc[q][p];
      if (mirror) Fb[(size_t)j * NF + i] = -acc[q][p];
    }
  }
}

// ---------------- edges ---------------
__global__ __launch_bounds__(256)
void fill_edges_k(const float* __restrict__ U, const int* __restrict__ idx,
                  float* __restrict__ Ff) {
  const int b = blockIdx.x;
  const int tid = threadIdx.x;
  float* Fb = Ff + (size_t)b * NF * NF;
  const int gr = idx[b * NE + tid];
#pragma unroll 4
  for (int u = 0; u < NUN; ++u) {
    float v = U[(size_t)gr * NFM + u];
    Fb[(size_t)tid * NF + NE + u] = v;
    Fb[(size_t)(NE + u) * NF + tid] = -v;
  }
  if (tid < NUN) {
    for (int v = 0; v < NUN; ++v) Fb[(size_t)(NE + tid) * NF + NE + v] = 0.f;
  }
}

// ---- pivot accumulator: prod *= piv with exponent renormalization ----
#define ACC_PIVOT(piv)                                                \
  do {                                                                \
    prod *= (piv);                                                    \
    unsigned u_ = __float_as_uint(prod);                              \
    int e_ = (int)((u_ >> 23) & 0xFFu);                               \
    if (e_ > 0 && e_ < 255) {                                         \
      eacc += e_ - 127;                                               \
      prod = __uint_as_float((u_ & 0x807FFFFFu) | (127u << 23));      \
    }                                                                 \
  } while (0)

// ---- rtc[m] = v for runtime m, via masked static unroll (no scratch) ----
#define RTC_SET(mm, vx, vy)                                           \
  do {                                                                \
    _Pragma("unroll")                                                 \
    for (int m_ = 0; m_ < PAIRS; ++m_)                                \
      if (m_ == (mm)) { rtc[m_].x = (vx); rtc[m_].y = (vy); }         \
  } while (0)

// ---------------- Pfaffian: R22 + register-cached own (nu,c) history --------
__global__ __launch_bounds__(512)
void pfpanel_k(float* __restrict__ Ff, float* __restrict__ out) {
  const int b = blockIdx.x;
  float* __restrict__ A = Ff + (size_t)b * NF * NF;
  const int tid = threadIdx.x;
  __shared__ __align__(16) float P[NF * PP];
  __shared__ __align__(16) float2 s_tc[PAIRS][NF];   // (nu, c) RAW
  __shared__ __align__(16) float s_colbuf[NF];
  __shared__ float s_oldrow[WP];
  __shared__ float s_pivdef[2];
  __shared__ float s_invp[PAIRS];
  __shared__ __align__(16) unsigned s_redu[2][8];

  float prod = 1.f;   // running pivot product (renormalized), thread 0 only
  int eacc = 0;       // accumulated exponent
  int nswap = 0;      // swap parity
  float2 rtc[PAIRS];  // this thread's own (nu,c) per pair (mirror of s_tc[m][tid])

#pragma unroll 1
  for (int k0 = 0; k0 < NF; k0 += WP) {
    const int pend = k0 + WP;

    if (k0 == 0) {
      for (int e = tid; e < NF * 4; e += 512) {
        int r = e >> 2, c4 = (e & 3) << 2;
        float4 v = *(const float4*)(A + (size_t)r * NF + c4);
        float2* d = (float2*)&P[r * PP + c4];
        d[0] = make_float2(v.x, v.y);
        d[1] = make_float2(v.z, v.w);
      }
      __syncthreads();
    }

#pragma unroll 1
    for (int mp = 0; mp < PAIRS; ++mp) {
      const int k = k0 + 2 * mp, lc = 2 * mp, lc1 = lc + 1;
      const int par = mp & 1;

      // ---- phase 1: pair cols + corrections (reg own-pair + LDS bcast) ----
      float vk = 0.f, vk1 = 0.f;
      unsigned pk = 0;
      if (tid > k && tid < NF) {
        float2 pv = *(const float2*)&P[tid * PP + lc];
        vk = pv.x; vk1 = pv.y;
        if (mp > 0) {
#pragma unroll
          for (int m = 0; m < 4; ++m) {
            float2 ti  = rtc[m];
            float4 tkq = *(const float4*)(&s_tc[m][k]);   // (tk, tk1) bcast
            float im = s_invp[m];
            float d0 = im * (ti.x * tkq.y - ti.y * tkq.x);
            float d1 = im * (ti.x * tkq.w - ti.y * tkq.z);
            vk  += (m < mp) ? d0 : 0.f;
            vk1 += (m < mp) ? d1 : 0.f;
          }
        }
        if (mp > 4) {
#pragma unroll
          for (int m = 4; m < 7; ++m) {
            float2 ti  = rtc[m];
            float4 tkq = *(const float4*)(&s_tc[m][k]);
            float im = s_invp[m];
            float d0 = im * (ti.x * tkq.y - ti.y * tkq.x);
            float d1 = im * (ti.x * tkq.w - ti.y * tkq.z);
            vk  += (m < mp) ? d0 : 0.f;
            vk1 += (m < mp) ? d1 : 0.f;
          }
        }
        s_colbuf[tid] = vk;
        if (tid > k + 1) {
          s_tc[mp][tid] = make_float2(-vk, vk1);          // spec, RAW
          RTC_SET(mp, -vk, vk1);
        } else {
          s_pivdef[par] = vk;                             // tid == k+1
        }
        pk = (__float_as_uint(fabsf(vk)) & 0xFFFFFE00u) | (unsigned)tid;
      }
#pragma unroll
      for (int s = 32; s > 0; s >>= 1) {
        unsigned o = (unsigned)__shfl_xor((int)pk, s, 64);
        if (o > pk) pk = o;
      }
      if ((tid & 63) == 0) s_redu[par][tid >> 6] = pk;
      __syncthreads();                                    // B1 (only barrier)
      uint4 r0 = *(const uint4*)&s_redu[par][0];
      uint4 r1 = *(const uint4*)&s_redu[par][4];
      unsigned best = r0.x;
      best = best > r0.y ? best : r0.y;
      best = best > r0.z ? best : r0.z;
      best = best > r0.w ? best : r0.w;
      best = best > r1.x ? best : r1.x;
      best = best > r1.y ? best : r1.y;
      best = best > r1.z ? best : r1.z;
      best = best > r1.w ? best : r1.w;
      const float vmax = __uint_as_float(best & 0xFFFFFE00u);
      const float pivdef = -s_pivdef[par];
      const bool doswap = fabsf(pivdef) < THETA * vmax;

      if (!doswap) {
        // ========== common path: pivot = pivdef, NO extra LDS loads ========
        const float invp = 1.f / pivdef;
        s_invp[mp] = invp;
        if (tid == 0) ACC_PIVOT(pivdef);
      } else {
        const int kp = (int)(best & 0x1FFu);
        const float pivot = -s_colbuf[kp];
        const float invp = 1.f / pivot;
        s_invp[mp] = invp;
        if (tid == 0) { nswap++; ACC_PIVOT(pivot); }
        const bool inpanel = (kp < pend);
        float gvr = 0.f;
        if (inpanel) {
          // ---- case B: in-panel swap ----
          const int lckp = kp - k0;
          if (tid > k + 1 && tid < NF && tid != kp) {
            float a = P[tid * PP + lc1], b2 = P[tid * PP + lckp];
            P[tid * PP + lc1] = b2; P[tid * PP + lckp] = a;
          } else if (tid >= NF && tid < NF + WP) {
            int c = tid - NF;
            if (c != lc1 && c != lckp) {
              float a = P[(k + 1) * PP + c], b2 = P[kp * PP + c];
              P[(k + 1) * PP + c] = b2; P[kp * PP + c] = a;
            }
          } else if (tid == NF + WP) {
            float a = P[kp * PP + lc1];         // old A[kp][k+1]
            float b2 = P[(k + 1) * PP + lckp];  // old A[k+1][kp]
            P[(k + 1) * PP + lc1] = 0.f;  P[(k + 1) * PP + lckp] = a;
            P[kp * PP + lc1] = b2;        P[kp * PP + lckp] = 0.f;
          } else if (tid >= NF + 24 && tid < NF + 24 + mp) {
            int m = tid - (NF + 24);
            float2 a = s_tc[m][k + 1], b2 = s_tc[m][kp];
            s_tc[m][k + 1] = b2; s_tc[m][kp] = a;
          }
        } else {
          // ---- case C: trailing swap, snapshot-consistent writeback ----
          if (tid >= pend && tid < NF) {
            if (tid == kp) {
              A[(size_t)kp * NF + kp] = 0.f;
            } else {
              float pvv = P[tid * PP + lc1];
              gvr = A[(size_t)tid * NF + kp];
              A[(size_t)tid * NF + kp] = pvv;
              A[(size_t)kp * NF + tid] = -pvv;
            }
          } else if (tid >= NF && tid < NF + WP) {
            int c = tid - NF;
            float old = P[kp * PP + c];
            s_oldrow[c] = old;
            P[kp * PP + c] = P[(k + 1) * PP + c];
          } else if (tid >= NF + 24 && tid < NF + 24 + mp) {
            int m = tid - (NF + 24);
            float2 a = s_tc[m][k + 1], b2 = s_tc[m][kp];
            s_tc[m][k + 1] = b2; s_tc[m][kp] = a;
          }
        }
        __syncthreads();                                  // B2
        if (tid > k + 1 && tid < NF) {
          // thread kp's past-pair registers went stale (entry swap) — reload
          if (tid == kp) {
#pragma unroll
            for (int m = 0; m < PAIRS - 1; ++m)
              if (m < mp) rtc[m] = s_tc[m][tid];
          }
          float vpost = (tid == kp) ? s_colbuf[k + 1] : vk;
          float cc;
          if (inpanel)        cc = P[tid * PP + lc1];
          else if (tid < pend) cc = -s_oldrow[tid - k0];
          else if (tid == kp)  cc = -s_oldrow[lc1];
          else                 cc = gvr;
#pragma unroll
          for (int m = 0; m < PAIRS - 1; ++m) {
            if (m < mp) {
              const float im = s_invp[m];
              float2 ti = rtc[m], tk1 = s_tc[m][k + 1];
              cc = fmaf(ti.x, im * tk1.y, fmaf(-ti.y, im * tk1.x, cc));
            }
          }
          s_tc[mp][tid] = make_float2(-vpost, cc);        // RAW
          RTC_SET(mp, -vpost, cc);
        }
        __syncthreads();                                  // B3
      }
    }
    __syncthreads();   // all pairs staged + swap-path P reads done

    // ---- panel-end: single-pass j-outer trailing, 4-deep batched RMW ------
    if (pend < NF) {
      const int ty = tid >> 6, tx = tid & 63;   // 8 row streams x 64 col chunks
      const int nch = (NF - pend) >> 2;
      float ivr[PAIRS];
#pragma unroll
      for (int m = 0; m < PAIRS; ++m) ivr[m] = s_invp[m];
      for (int jb = 0; jb < nch; jb += 64) {
        const int j4 = jb + tx;
        if (j4 < nch) {
          const int j = pend + (j4 << 2);
          const bool stageP = (j4 < (WP >> 2));
          float4 tj[PAIRS], cj[PAIRS];
#pragma unroll
          for (int m = 0; m < PAIRS; ++m) {
            const float im = ivr[m];
            float4 q0 = *(const float4*)(&s_tc[m][j]);
            float4 q1 = *(const float4*)(&s_tc[m][j + 2]);
            tj[m] = make_float4(q0.x * im, q0.z * im, q1.x * im, q1.z * im);
            cj[m] = make_float4(q0.y * im, q0.w * im, q1.y * im, q1.w * im);
          }
          for (int i0 = pend + ty; i0 < NF; i0 += 32) {
            const int i1 = i0 + 8, i2 = i0 + 16, i3 = i0 + 24;
            const bool v1 = i1 < NF, v2 = i2 < NF, v3 = i3 < NF;
            const int ii1 = v1 ? i1 : i0, ii2 = v2 ? i2 : i0, ii3 = v3 ? i3 : i0;
            float* p0 = A + (size_t)i0 * NF + j;
            float* p1 = A + (size_t)ii1 * NF + j;
            float* p2 = A + (size_t)ii2 * NF + j;
            float* p3 = A + (size_t)ii3 * NF + j;
            float4 a0 = *(float4*)p0;
            float4 a1 = *(float4*)p1;
            float4 a2 = *(float4*)p2;
            float4 a3 = *(float4*)p3;
#pragma unroll
            for (int m = 0; m < PAIRS; ++m) {
              const float2 t0 = s_tc[m][i0];
              const float2 t1 = s_tc[m][ii1];
              const float2 t2 = s_tc[m][ii2];
              const float2 t3 = s_tc[m][ii3];
              a0.x = fmaf(t0.x, cj[m].x, fmaf(-t0.y, tj[m].x, a0.x));
              a0.y = fmaf(t0.x, cj[m].y, fmaf(-t0.y, tj[m].y, a0.y));
              a0.z = fmaf(t0.x, cj[m].z, fmaf(-t0.y, tj[m].z, a0.z));
              a0.w = fmaf(t0.x, cj[m].w, fmaf(-t0.y, tj[m].w, a0.w));
              a1.x = fmaf(t1.x, cj[m].x, fmaf(-t1.y, tj[m].x, a1.x));
              a1.y = fmaf(t1.x, cj[m].y, fmaf(-t1.y, tj[m].y, a1.y));
              a1.z = fmaf(t1.x, cj[m].z, fmaf(-t1.y, tj[m].z, a1.z));
              a1.w = fmaf(t1.x, cj[m].w, fmaf(-t1.y, tj[m].w, a1.w));
              a2.x = fmaf(t2.x, cj[m].x, fmaf(-t2.y, tj[m].x, a2.x));
              a2.y = fmaf(t2.x, cj[m].y, fmaf(-t2.y, tj[m].y, a2.y));
              a2.z = fmaf(t2.x, cj[m].z, fmaf(-t2.y, tj[m].z, a2.z));
              a2.w = fmaf(t2.x, cj[m].w, fmaf(-t2.y, tj[m].w, a2.w));
              a3.x = fmaf(t3.x, cj[m].x, fmaf(-t3.y, tj[m].x, a3.x));
              a3.y = fmaf(t3.x, cj[m].y, fmaf(-t3.y, tj[m].y, a3.y));
              a3.z = fmaf(t3.x, cj[m].z, fmaf(-t3.y, tj[m].z, a3.z));
              a3.w = fmaf(t3.x, cj[m].w, fmaf(-t3.y, tj[m].w, a3.w));
            }
            *(float4*)p0 = a0;
            if (v1) *(float4*)p1 = a1;
            if (v2) *(float4*)p2 = a2;
            if (v3) *(float4*)p3 = a3;
            if (stageP) {
              const int pc = j - pend;
              float2* d0 = (float2*)&P[i0 * PP + pc];
              d0[0] = make_float2(a0.x, a0.y); d0[1] = make_float2(a0.z, a0.w);
              if (v1) { float2* d = (float2*)&P[i1 * PP + pc];
                        d[0] = make_float2(a1.x, a1.y); d[1] = make_float2(a1.z, a1.w); }
              if (v2) { float2* d = (float2*)&P[i2 * PP + pc];
                        d[0] = make_float2(a2.x, a2.y); d[1] = make_float2(a2.z, a2.w); }
              if (v3) { float2* d = (float2*)&P[i3 * PP + pc];
                        d[0] = make_float2(a3.x, a3.y); d[1] = make_float2(a3.z, a3.w); }
            }
          }
        }
      }
    }
    __syncthreads();   // trailing + P staging visible before next factor
  }

  if (tid == 0) {
    float sgn = (prod > 0.f ? 1.f : (prod < 0.f ? -1.f : 0.f));
    if (nswap & 1) sgn = -sgn;
    out[b] = sgn;
    out[NB + b] = logf(fabsf(prod)) + (float)eacc * 0.6931471805599453f;
  }
}

extern "C" void kernel_launch(void* const* d_in, const int* in_sizes, int n_in,
                              void* d_out, int out_size, void* d_ws, size_t ws_size,
                              hipStream_t stream) {
  const float* U  = (const float*)d_in[0];
  const float* J  = (const float*)d_in[1];
  const int* idx  = (const int*)d_in[2];
  float* out = (float*)d_out;
  float* ws = (float*)d_ws;

  float* Ja = ws;                           // 480*480   = 230400 floats
  float* W  = Ja + (size_t)NM * NM;         // 512*480   = 245760 floats
  float* Ff = W + (size_t)NFM * NM;         // 32*288*288

  build_ja_k<<<dim3(256), dim3(256), 0, stream>>>(J, Ja);
  gemm_w_k<<<dim3(8, 8), dim3(256), 0, stream>>>(U, Ja, W);
  gemm2_k<<<dim3(4, 4, NB), dim3(256), 0, stream>>>(U, idx, W, Ff);
  fill_edges_k<<<dim3(NB), dim3(256), 0, stream>>>(U, idx, Ff);
  pfpanel_k<<<dim3(NB), dim3(512), 0, stream>>>(Ff, out);
}

// Round 24
// 302.334 us; speedup vs baseline: 1.0216x; 1.0216x over previous
//
#include <hip/hip_runtime.h>
#include <hip/hip_bf16.h>
#include <math.h>

#define NFM 512   // NFMODES
#define NE  256
#define NUN 32    // NUNPAIRED
#define NM  480   // NMODES
#define NB  32    // BATCH
#define NF  288   // NE + NUN  (Ffull dim)
#define WP  16    // panel width
#define PAIRS 8   // WP/2
#define PP  18    // panel LDS pitch (even -> float2-aligned)
#define THETA 0.03125f

typedef unsigned long long ull;

// ---------------- Ja = (J - J^T)/2 ----------------
__global__ __launch_bounds__(256)
void build_ja_k(const float* __restrict__ J, float* __restrict__ Ja) {
  int t = blockIdx.x * blockDim.x + threadIdx.x;
  int stride = gridDim.x * blockDim.x;
  for (int e = t; e < NM * NM; e += stride) {
    int i = e / NM, j = e - i * NM;
    Ja[e] = 0.5f * (J[i * NM + j] - J[j * NM + i]);
  }
}

// ---------------- W (512x480) = U[:, NUN:] @ Ja  (once, batch-independent) --
__global__ __launch_bounds__(256)
void gemm_w_k(const float* __restrict__ U, const float* __restrict__ Ja,
              float* __restrict__ W) {
  const int m0 = blockIdx.y << 6;
  const int n0 = blockIdx.x << 6;
  const int tid = threadIdx.x;
  __shared__ float As[16][64];
  __shared__ float Bs[16][64];
  const int ar = tid >> 2, ac = (tid & 3) << 2;
  const int br = tid >> 4, bc = (tid & 15) << 2;
  const int tx = tid & 15, ty = tid >> 4;
  const float* Arow = U + (size_t)(m0 + ar) * NFM + NUN;
  float acc[4][4] = {};
  for (int l0 = 0; l0 < NM; l0 += 16) {
    float4 av = *(const float4*)(Arow + l0 + ac);
    As[ac + 0][ar] = av.x; As[ac + 1][ar] = av.y;
    As[ac + 2][ar] = av.z; As[ac + 3][ar] = av.w;
    float4 bv = make_float4(0.f, 0.f, 0.f, 0.f);
    if (n0 + bc < NM) bv = *(const float4*)(Ja + (size_t)(l0 + br) * NM + n0 + bc);
    *(float4*)(&Bs[br][bc]) = bv;
    __syncthreads();
#pragma unroll
    for (int kk = 0; kk < 16; ++kk) {
      float4 a4 = *(const float4*)(&As[kk][ty << 2]);
      float4 b4 = *(const float4*)(&Bs[kk][tx << 2]);
      float a[4] = {a4.x, a4.y, a4.z, a4.w};
      float bb[4] = {b4.x, b4.y, b4.z, b4.w};
#pragma unroll
      for (int q = 0; q < 4; ++q)
#pragma unroll
        for (int p = 0; p < 4; ++p) acc[q][p] = fmaf(a[q], bb[p], acc[q][p]);
    }
    __syncthreads();
  }
#pragma unroll
  for (int q = 0; q < 4; ++q) {
    int r = m0 + (ty << 2) + q;
#pragma unroll
    for (int p = 0; p < 4; ++p) {
      int m = n0 + (tx << 2) + p;
      if (m < NM) W[(size_t)r * NM + m] = acc[q][p];
    }
  }
}

// ---------------- F[b] = W[idx[b]] @ Up_b^T  -> Ffull[0:256][0:256] ---------
// Antisymmetric: only blocks by>=bx computed; off-diagonal mirror-written.
__global__ __launch_bounds__(256)
void gemm2_k(const float* __restrict__ U, const int* __restrict__ idx,
             const float* __restrict__ W, float* __restrict__ Ff) {
  const int b  = blockIdx.z;
  const int by = blockIdx.y, bx = blockIdx.x;
  if (by < bx) return;
  const int m0 = by << 6;
  const int n0 = bx << 6;
  const int tid = threadIdx.x;
  __shared__ float As[16][64];
  __shared__ float Bs[16][64];
  const int ar = tid >> 2, ac = (tid & 3) << 2;
  const int jr = tid >> 2, kc = (tid & 3) << 2;
  const int tx = tid & 15, ty = tid >> 4;
  const float* Arow = W + (size_t)idx[b * NE + m0 + ar] * NM;
  const float* Brow = U + (size_t)idx[b * NE + n0 + jr] * NFM + NUN;
  float acc[4][4] = {};
  for (int l0 = 0; l0 < NM; l0 += 16) {
    float4 av = *(const float4*)(Arow + l0 + ac);
    As[ac + 0][ar] = av.x; As[ac + 1][ar] = av.y;
    As[ac + 2][ar] = av.z; As[ac + 3][ar] = av.w;
    float4 bv = *(const float4*)(Brow + l0 + kc);
    Bs[kc + 0][jr] = bv.x; Bs[kc + 1][jr] = bv.y;
    Bs[kc + 2][jr] = bv.z; Bs[kc + 3][jr] = bv.w;
    __syncthreads();
#pragma unroll
    for (int kk = 0; kk < 16; ++kk) {
      float4 a4 = *(const float4*)(&As[kk][ty << 2]);
      float4 b4 = *(const float4*)(&Bs[kk][tx << 2]);
      float a[4] = {a4.x, a4.y, a4.z, a4.w};
      float bb[4] = {b4.x, b4.y, b4.z, b4.w};
#pragma unroll
      for (int q = 0; q < 4; ++q)
#pragma unroll
        for (int p = 0; p < 4; ++p) acc[q][p] = fmaf(a[q], bb[p], acc[q][p]);
    }
    __syncthreads();
  }
  float* Fb = Ff + (size_t)b * NF * NF;
  const bool mirror = (by > bx);
#pragma unroll
  for (int q = 0; q < 4; ++q) {
    int i = m0 + (ty << 2) + q;
#pragma unroll
    for (int p = 0; p < 4; ++p) {
      int j = n0 + (tx << 2) + p;
      Fb[(size_t)i * NF + j] = acc[q][p];
      if (mirror) Fb[(size_t)j * NF + i] = -acc[q][p];
    }
  }
}

// ---------------- edges ---------------
__global__ __launch_bounds__(256)
void fill_edges_k(const float* __restrict__ U, const int* __restrict__ idx,
                  float* __restrict__ Ff) {
  const int b = blockIdx.x;
  const int tid = threadIdx.x;
  float* Fb = Ff + (size_t)b * NF * NF;
  const int gr = idx[b * NE + tid];
#pragma unroll 4
  for (int u = 0; u < NUN; ++u) {
    float v = U[(size_t)gr * NFM + u];
    Fb[(size_t)tid * NF + NE + u] = v;
    Fb[(size_t)(NE + u) * NF + tid] = -v;
  }
  if (tid < NUN) {
    for (int v = 0; v < NUN; ++v) Fb[(size_t)(NE + tid) * NF + NE + v] = 0.f;
  }
}

// ---- pivot accumulator: prod *= piv with exponent renormalization ----
#define ACC_PIVOT(piv)                                                \
  do {                                                                \
    prod *= (piv);                                                    \
    unsigned u_ = __float_as_uint(prod);                              \
    int e_ = (int)((u_ >> 23) & 0xFFu);                               \
    if (e_ > 0 && e_ < 255) {                                         \
      eacc += e_ - 127;                                               \
      prod = __uint_as_float((u_ & 0x807FFFFFu) | (127u << 23));      \
    }                                                                 \
  } while (0)

// ---------------- Pfaffian: R22 kernel (measured best) + dead-store skip ----
// stageP chunks write P only; their global copy is never read again
// (case-C touches kp >= pend; next trailing RMW reads i,j >= pend+WP).
__global__ __launch_bounds__(512)
void pfpanel_k(float* __restrict__ Ff, float* __restrict__ out) {
  const int b = blockIdx.x;
  float* __restrict__ A = Ff + (size_t)b * NF * NF;
  const int tid = threadIdx.x;
  __shared__ __align__(16) float P[NF * PP];
  __shared__ __align__(16) float2 s_tc[PAIRS][NF];   // (nu, c) RAW
  __shared__ __align__(16) float s_colbuf[NF];
  __shared__ float s_oldrow[WP];
  __shared__ float s_pivdef[2];
  __shared__ float s_invp[PAIRS];
  __shared__ __align__(16) unsigned s_redu[2][8];

  float prod = 1.f;   // running pivot product (renormalized), thread 0 only
  int eacc = 0;       // accumulated exponent
  int nswap = 0;      // swap parity

#pragma unroll 1
  for (int k0 = 0; k0 < NF; k0 += WP) {
    const int pend = k0 + WP;

    if (k0 == 0) {
      for (int e = tid; e < NF * 4; e += 512) {
        int r = e >> 2, c4 = (e & 3) << 2;
        float4 v = *(const float4*)(A + (size_t)r * NF + c4);
        float2* d = (float2*)&P[r * PP + c4];
        d[0] = make_float2(v.x, v.y);
        d[1] = make_float2(v.z, v.w);
      }
      __syncthreads();
    }

#pragma unroll 1
    for (int mp = 0; mp < PAIRS; ++mp) {
      const int k = k0 + 2 * mp, lc = 2 * mp, lc1 = lc + 1;
      const int par = mp & 1;

      // ---- phase 1: pair cols + exact-count corrections (fused bcast) ----
      float vk = 0.f, vk1 = 0.f;
      unsigned pk = 0;
      if (tid > k && tid < NF) {
        float2 pv = *(const float2*)&P[tid * PP + lc];
        vk = pv.x; vk1 = pv.y;
        if (mp > 0) {
#pragma unroll
          for (int m = 0; m < 4; ++m) {
            float2 ti  = s_tc[m][tid];
            float4 tkq = *(const float4*)(&s_tc[m][k]);   // (tk.x,tk.y,tk1.x,tk1.y)
            float im = s_invp[m];
            float d0 = im * (ti.x * tkq.y - ti.y * tkq.x);
            float d1 = im * (ti.x * tkq.w - ti.y * tkq.z);
            vk  += (m < mp) ? d0 : 0.f;
            vk1 += (m < mp) ? d1 : 0.f;
          }
        }
        if (mp > 4) {
#pragma unroll
          for (int m = 4; m < 7; ++m) {
            float2 ti  = s_tc[m][tid];
            float4 tkq = *(const float4*)(&s_tc[m][k]);
            float im = s_invp[m];
            float d0 = im * (ti.x * tkq.y - ti.y * tkq.x);
            float d1 = im * (ti.x * tkq.w - ti.y * tkq.z);
            vk  += (m < mp) ? d0 : 0.f;
            vk1 += (m < mp) ? d1 : 0.f;
          }
        }
        s_colbuf[tid] = vk;
        if (tid > k + 1) s_tc[mp][tid] = make_float2(-vk, vk1);  // spec, RAW
        else             s_pivdef[par] = vk;                     // tid == k+1
        pk = (__float_as_uint(fabsf(vk)) & 0xFFFFFE00u) | (unsigned)tid;
      }
#pragma unroll
      for (int s = 32; s > 0; s >>= 1) {
        unsigned o = (unsigned)__shfl_xor((int)pk, s, 64);
        if (o > pk) pk = o;
      }
      if ((tid & 63) == 0) s_redu[par][tid >> 6] = pk;
      __syncthreads();                                    // B1 (only barrier)
      uint4 r0 = *(const uint4*)&s_redu[par][0];
      uint4 r1 = *(const uint4*)&s_redu[par][4];
      unsigned best = r0.x;
      best = best > r0.y ? best : r0.y;
      best = best > r0.z ? best : r0.z;
      best = best > r0.w ? best : r0.w;
      best = best > r1.x ? best : r1.x;
      best = best > r1.y ? best : r1.y;
      best = best > r1.z ? best : r1.z;
      best = best > r1.w ? best : r1.w;
      const float vmax = __uint_as_float(best & 0xFFFFFE00u);
      const float pivdef = -s_pivdef[par];
      const bool doswap = fabsf(pivdef) < THETA * vmax;

      if (!doswap) {
        // ========== common path: pivot = pivdef, NO extra LDS loads ========
        const float invp = 1.f / pivdef;
        s_invp[mp] = invp;
        if (tid == 0) ACC_PIVOT(pivdef);
      } else {
        const int kp = (int)(best & 0x1FFu);
        const float pivot = -s_colbuf[kp];
        const float invp = 1.f / pivot;
        s_invp[mp] = invp;
        if (tid == 0) { nswap++; ACC_PIVOT(pivot); }
        const bool inpanel = (kp < pend);
        float gvr = 0.f;
        if (inpanel) {
          // ---- case B: in-panel swap ----
          const int lckp = kp - k0;
          if (tid > k + 1 && tid < NF && tid != kp) {
            float a = P[tid * PP + lc1], b2 = P[tid * PP + lckp];
            P[tid * PP + lc1] = b2; P[tid * PP + lckp] = a;
          } else if (tid >= NF && tid < NF + WP) {
            int c = tid - NF;
            if (c != lc1 && c != lckp) {
              float a = P[(k + 1) * PP + c], b2 = P[kp * PP + c];
              P[(k + 1) * PP + c] = b2; P[kp * PP + c] = a;
            }
          } else if (tid == NF + WP) {
            float a = P[kp * PP + lc1];         // old A[kp][k+1]
            float b2 = P[(k + 1) * PP + lckp];  // old A[k+1][kp]
            P[(k + 1) * PP + lc1] = 0.f;  P[(k + 1) * PP + lckp] = a;
            P[kp * PP + lc1] = b2;        P[kp * PP + lckp] = 0.f;
          } else if (tid >= NF + 24 && tid < NF + 24 + mp) {
            int m = tid - (NF + 24);
            float2 a = s_tc[m][k + 1], b2 = s_tc[m][kp];
            s_tc[m][k + 1] = b2; s_tc[m][kp] = a;
          }
        } else {
          // ---- case C: trailing swap, snapshot-consistent writeback ----
          if (tid >= pend && tid < NF) {
            if (tid == kp) {
              A[(size_t)kp * NF + kp] = 0.f;
            } else {
              float pvv = P[tid * PP + lc1];
              gvr = A[(size_t)tid * NF + kp];
              A[(size_t)tid * NF + kp] = pvv;
              A[(size_t)kp * NF + tid] = -pvv;
            }
          } else if (tid >= NF && tid < NF + WP) {
            int c = tid - NF;
            float old = P[kp * PP + c];
            s_oldrow[c] = old;
            P[kp * PP + c] = P[(k + 1) * PP + c];
          } else if (tid >= NF + 24 && tid < NF + 24 + mp) {
            int m = tid - (NF + 24);
            float2 a = s_tc[m][k + 1], b2 = s_tc[m][kp];
            s_tc[m][k + 1] = b2; s_tc[m][kp] = a;
          }
        }
        __syncthreads();                                  // B2
        if (tid > k + 1 && tid < NF) {
          float vpost = (tid == kp) ? s_colbuf[k + 1] : vk;
          float cc;
          if (inpanel)        cc = P[tid * PP + lc1];
          else if (tid < pend) cc = -s_oldrow[tid - k0];
          else if (tid == kp)  cc = -s_oldrow[lc1];
          else                 cc = gvr;
#pragma unroll 1
          for (int m = 0; m < mp; ++m) {
            const float im = s_invp[m];
            float2 ti = s_tc[m][tid], tk1 = s_tc[m][k + 1];
            cc = fmaf(ti.x, im * tk1.y, fmaf(-ti.y, im * tk1.x, cc));
          }
          s_tc[mp][tid] = make_float2(-vpost, cc);        // RAW
        }
        __syncthreads();                                  // B3
      }
    }
    __syncthreads();   // all pairs staged + swap-path P reads done

    // ---- panel-end: single-pass j-outer trailing, 4-deep batched RMW ------
    // stageP chunks: write P only (their global copy is never read again).
    if (pend < NF) {
      const int ty = tid >> 6, tx = tid & 63;   // 8 row streams x 64 col chunks
      const int nch = (NF - pend) >> 2;
      float ivr[PAIRS];
#pragma unroll
      for (int m = 0; m < PAIRS; ++m) ivr[m] = s_invp[m];
      for (int jb = 0; jb < nch; jb += 64) {
        const int j4 = jb + tx;
        if (j4 < nch) {
          const int j = pend + (j4 << 2);
          const bool stageP = (j4 < (WP >> 2));
          float4 tj[PAIRS], cj[PAIRS];
#pragma unroll
          for (int m = 0; m < PAIRS; ++m) {
            const float im = ivr[m];
            float4 q0 = *(const float4*)(&s_tc[m][j]);
            float4 q1 = *(const float4*)(&s_tc[m][j + 2]);
            tj[m] = make_float4(q0.x * im, q0.z * im, q1.x * im, q1.z * im);
            cj[m] = make_float4(q0.y * im, q0.w * im, q1.y * im, q1.w * im);
          }
          for (int i0 = pend + ty; i0 < NF; i0 += 32) {
            const int i1 = i0 + 8, i2 = i0 + 16, i3 = i0 + 24;
            const bool v1 = i1 < NF, v2 = i2 < NF, v3 = i3 < NF;
            const int ii1 = v1 ? i1 : i0, ii2 = v2 ? i2 : i0, ii3 = v3 ? i3 : i0;
            float* p0 = A + (size_t)i0 * NF + j;
            float* p1 = A + (size_t)ii1 * NF + j;
            float* p2 = A + (size_t)ii2 * NF + j;
            float* p3 = A + (size_t)ii3 * NF + j;
            float4 a0 = *(float4*)p0;
            float4 a1 = *(float4*)p1;
            float4 a2 = *(float4*)p2;
            float4 a3 = *(float4*)p3;
#pragma unroll
            for (int m = 0; m < PAIRS; ++m) {
              const float2 t0 = s_tc[m][i0];
              const float2 t1 = s_tc[m][ii1];
              const float2 t2 = s_tc[m][ii2];
              const float2 t3 = s_tc[m][ii3];
              a0.x = fmaf(t0.x, cj[m].x, fmaf(-t0.y, tj[m].x, a0.x));
              a0.y = fmaf(t0.x, cj[m].y, fmaf(-t0.y, tj[m].y, a0.y));
              a0.z = fmaf(t0.x, cj[m].z, fmaf(-t0.y, tj[m].z, a0.z));
              a0.w = fmaf(t0.x, cj[m].w, fmaf(-t0.y, tj[m].w, a0.w));
              a1.x = fmaf(t1.x, cj[m].x, fmaf(-t1.y, tj[m].x, a1.x));
              a1.y = fmaf(t1.x, cj[m].y, fmaf(-t1.y, tj[m].y, a1.y));
              a1.z = fmaf(t1.x, cj[m].z, fmaf(-t1.y, tj[m].z, a1.z));
              a1.w = fmaf(t1.x, cj[m].w, fmaf(-t1.y, tj[m].w, a1.w));
              a2.x = fmaf(t2.x, cj[m].x, fmaf(-t2.y, tj[m].x, a2.x));
              a2.y = fmaf(t2.x, cj[m].y, fmaf(-t2.y, tj[m].y, a2.y));
              a2.z = fmaf(t2.x, cj[m].z, fmaf(-t2.y, tj[m].z, a2.z));
              a2.w = fmaf(t2.x, cj[m].w, fmaf(-t2.y, tj[m].w, a2.w));
              a3.x = fmaf(t3.x, cj[m].x, fmaf(-t3.y, tj[m].x, a3.x));
              a3.y = fmaf(t3.x, cj[m].y, fmaf(-t3.y, tj[m].y, a3.y));
              a3.z = fmaf(t3.x, cj[m].z, fmaf(-t3.y, tj[m].z, a3.z));
              a3.w = fmaf(t3.x, cj[m].w, fmaf(-t3.y, tj[m].w, a3.w));
            }
            if (!stageP) {
              *(float4*)p0 = a0;
              if (v1) *(float4*)p1 = a1;
              if (v2) *(float4*)p2 = a2;
              if (v3) *(float4*)p3 = a3;
            } else {
              const int pc = j - pend;
              float2* d0 = (float2*)&P[i0 * PP + pc];
              d0[0] = make_float2(a0.x, a0.y); d0[1] = make_float2(a0.z, a0.w);
              if (v1) { float2* d = (float2*)&P[i1 * PP + pc];
                        d[0] = make_float2(a1.x, a1.y); d[1] = make_float2(a1.z, a1.w); }
              if (v2) { float2* d = (float2*)&P[i2 * PP + pc];
                        d[0] = make_float2(a2.x, a2.y); d[1] = make_float2(a2.z, a2.w); }
              if (v3) { float2* d = (float2*)&P[i3 * PP + pc];
                        d[0] = make_float2(a3.x, a3.y); d[1] = make_float2(a3.z, a3.w); }
            }
          }
        }
      }
    }
    __syncthreads();   // trailing + P staging visible before next factor
  }

  if (tid == 0) {
    float sgn = (prod > 0.f ? 1.f : (prod < 0.f ? -1.f : 0.f));
    if (nswap & 1) sgn = -sgn;
    out[b] = sgn;
    out[NB + b] = logf(fabsf(prod)) + (float)eacc * 0.6931471805599453f;
  }
}

extern "C" void kernel_launch(void* const* d_in, const int* in_sizes, int n_in,
                              void* d_out, int out_size, void* d_ws, size_t ws_size,
                              hipStream_t stream) {
  const float* U  = (const float*)d_in[0];
  const float* J  = (const float*)d_in[1];
  const int* idx  = (const int*)d_in[2];
  float* out = (float*)d_out;
  float* ws = (float*)d_ws;

  float* Ja = ws;                           // 480*480   = 230400 floats
  float* W  = Ja + (size_t)NM * NM;         // 512*480   = 245760 floats
  float* Ff = W + (size_t)NFM * NM;         // 32*288*288

  build_ja_k<<<dim3(256), dim3(256), 0, stream>>>(J, Ja);
  gemm_w_k<<<dim3(8, 8), dim3(256), 0, stream>>>(U, Ja, W);
  gemm2_k<<<dim3(4, 4, NB), dim3(256), 0, stream>>>(U, idx, W, Ff);
  fill_edges_k<<<dim3(NB), dim3(256), 0, stream>>>(U, idx, Ff);
  pfpanel_k<<<dim3(NB), dim3(512), 0, stream>>>(Ff, out);
}